// Round 3
// baseline (819.637 us; speedup 1.0000x reference)
//
#include <hip/hip_runtime.h>
#include <hip/hip_bf16.h>
#include <math.h>

typedef __bf16 bf16x8 __attribute__((ext_vector_type(8)));
typedef float floatx4 __attribute__((ext_vector_type(4)));

#define T_TOK 4096
#define H_DIM 1024
#define F_DIM 3584
#define E_NUM 8
#define NSLOT 8192  // T_TOK * 2

__device__ __forceinline__ void gload_lds16(const void* g, void* l) {
  __builtin_amdgcn_global_load_lds((const __attribute__((address_space(1))) void*)g,
                                   (__attribute__((address_space(3))) void*)l, 16, 0, 0);
}

__device__ __forceinline__ uint2 pack_bf16x4(float4 v) {
  union {
    unsigned short us[4];
    uint2 u;
  } pk;
  __hip_bfloat16 h0 = __float2bfloat16(v.x);
  __hip_bfloat16 h1 = __float2bfloat16(v.y);
  __hip_bfloat16 h2 = __float2bfloat16(v.z);
  __hip_bfloat16 h3 = __float2bfloat16(v.w);
  pk.us[0] = *(const unsigned short*)&h0;
  pk.us[1] = *(const unsigned short*)&h1;
  pk.us[2] = *(const unsigned short*)&h2;
  pk.us[3] = *(const unsigned short*)&h3;
  return pk.u;
}

// ---------------- K0: cast the three weight tensors fp32 -> bf16, one launch ----------------
__global__ __launch_bounds__(256) void k_cast3(const float* __restrict__ a,
                                               const float* __restrict__ b,
                                               const float* __restrict__ c,
                                               __hip_bfloat16* __restrict__ oa,
                                               __hip_bfloat16* __restrict__ ob,
                                               __hip_bfloat16* __restrict__ oc, int n4) {
  int i = blockIdx.x * 256 + threadIdx.x;
  const float* src;
  __hip_bfloat16* dst;
  if (i < n4) {
    src = a;
    dst = oa;
  } else if (i < 2 * n4) {
    src = b;
    dst = ob;
    i -= n4;
  } else {
    src = c;
    dst = oc;
    i -= 2 * n4;
  }
  float4 v = ((const float4*)src)[i];
  ((uint2*)dst)[i] = pack_bf16x4(v);
}

// ---------------- K1: router (logits, softmax top-2, counts) + fused x cast ----------------
__global__ __launch_bounds__(256) void k_router(const float* __restrict__ x,
                                                const float* __restrict__ gw,
                                                __hip_bfloat16* __restrict__ xb,
                                                int* __restrict__ count,
                                                int* __restrict__ top2e,
                                                float* __restrict__ top2w) {
  const int lane = threadIdx.x & 63;
  const int wv = threadIdx.x >> 6;
  const int t = blockIdx.x * 4 + wv;
  const float4* xv = (const float4*)(x + (size_t)t * H_DIM);
  float4 xa[4];
#pragma unroll
  for (int p = 0; p < 4; ++p) xa[p] = xv[lane + p * 64];
  uint2* xo = (uint2*)(xb + (size_t)t * H_DIM);
#pragma unroll
  for (int p = 0; p < 4; ++p) xo[lane + p * 64] = pack_bf16x4(xa[p]);
  float s[E_NUM];
#pragma unroll
  for (int e = 0; e < E_NUM; ++e) {
    const float4* gv = (const float4*)(gw + e * H_DIM);
    float acc = 0.f;
#pragma unroll
    for (int p = 0; p < 4; ++p) {
      float4 g = gv[lane + p * 64];
      acc += xa[p].x * g.x + xa[p].y * g.y + xa[p].z * g.z + xa[p].w * g.w;
    }
    s[e] = acc;
  }
#pragma unroll
  for (int e = 0; e < E_NUM; ++e) {
#pragma unroll
    for (int m = 32; m; m >>= 1) s[e] += __shfl_xor(s[e], m);
  }
  if (lane == 0) {
    int e0 = 0;
    float l0 = s[0];
    for (int e = 1; e < E_NUM; ++e)
      if (s[e] > l0) { l0 = s[e]; e0 = e; }
    int e1 = (e0 == 0) ? 1 : 0;
    float l1 = s[e1];
    for (int e = 0; e < E_NUM; ++e)
      if (e != e0 && s[e] > l1) { l1 = s[e]; e1 = e; }
    float w0 = 1.f / (1.f + __expf(l1 - l0));
    float w1 = 1.f - w0;
    atomicAdd(&count[e0], 1);
    atomicAdd(&count[e1], 1);
    top2e[2 * t] = e0;
    top2e[2 * t + 1] = e1;
    top2w[2 * t] = w0;
    top2w[2 * t + 1] = w1;
  }
}

// ---------------- K2: exclusive scan of 8 counts ----------------
__global__ void k_scan(const int* __restrict__ count, int* __restrict__ offs) {
  if (threadIdx.x == 0) {
    int a = 0;
    for (int e = 0; e < E_NUM; ++e) { offs[e] = a; a += count[e]; }
  }
}

// ---------------- K3: slot assignment ----------------
__global__ __launch_bounds__(256) void k_assign(const int* __restrict__ top2e,
                                                const float* __restrict__ top2w,
                                                const int* __restrict__ offs,
                                                int* __restrict__ cursor,
                                                int* __restrict__ tok_of_slot,
                                                float* __restrict__ w_of_slot,
                                                int* __restrict__ slot_of_tok) {
  const int t = blockIdx.x * 256 + threadIdx.x;
#pragma unroll
  for (int k = 0; k < 2; ++k) {
    int e = top2e[2 * t + k];
    int pos = atomicAdd(&cursor[e], 1);
    int slot = offs[e] + pos;
    tok_of_slot[slot] = t;
    w_of_slot[slot] = top2w[2 * t + k];
    slot_of_tok[2 * t + k] = slot;
  }
}

// ---------------- K4: grouped GEMM1: 256 slots x 128 B-rows (64 F-cols w1/w3), BK=64 ----------------
// 512 threads = 8 waves (4M x 2N), wave tile 64 rows x 64 B-rows, acc[4][4].
// 3-buffer LDS rotation (48KB each): tile kt in buf[kt%3], stage kt+2 into buf[(kt+2)%3].
// One vmcnt(6)+barrier per K-tile; prefetch window = 2 full K-steps.
// XCD-bijective block swizzle: each XCD owns one expert, y (M-panel) fastest -> B-panel L2 reuse.
__global__ __launch_bounds__(512, 2) void k_gemm1(const __hip_bfloat16* __restrict__ x,
                                                  const __hip_bfloat16* __restrict__ w1,
                                                  const __hip_bfloat16* __restrict__ w3,
                                                  const int* __restrict__ count,
                                                  const int* __restrict__ offs,
                                                  const int* __restrict__ tok_of_slot,
                                                  __hip_bfloat16* __restrict__ hbuf) {
  // launched grid (56, 16, 8) -> remap: wg = (lin%8)*896 + lin/8; y fastest, then x, then z
  const int lin = blockIdx.x + 56 * blockIdx.y + 896 * blockIdx.z;
  const int wg = (lin & 7) * 896 + (lin >> 3);
  const int yb = wg & 15;
  const int tq = wg >> 4;  // 0..447
  const int xb = tq % 56;
  const int e = tq / 56;
  const int Ne = count[e];
  const int mBase = yb * 256;
  if (mBase >= Ne) return;
  const int offE = offs[e];
  const int n0e = xb * 64;       // F-col base (64 F-cols per block)
  __shared__ char smem[147456];  // 3 x (A 32K | B 16K)
  const int tid = threadIdx.x, lane = tid & 63, wv = tid >> 6;
  const int wm = wv >> 1, wn = wv & 1;
  const int chunk = (((tid & 7) ^ ((tid >> 3) & 7)) * 8);  // XOR-swizzled source chunk (elems)

  // A sources: 4 sweeps of 64 rows (8 threads/row)
  const __hip_bfloat16* aSrc[4];
#pragma unroll
  for (int j = 0; j < 4; ++j) {
    int rl = j * 64 + (tid >> 3);
    int slot = offE + mBase + rl;
    if (slot > NSLOT - 1) slot = NSLOT - 1;
    int tok = tok_of_slot[slot];
    aSrc[j] = x + (size_t)tok * H_DIM + chunk;
  }
  // B sources: 2 sweeps of 64 rows; B-row br: group g=br>>4 (even->w1, odd->w3),
  // F-col = n0e + (br>>5)*16 + (br&15)
  const __hip_bfloat16* bSrc[2];
#pragma unroll
  for (int j = 0; j < 2; ++j) {
    int br = j * 64 + (tid >> 3);
    int g = br >> 4;
    int f = n0e + (br >> 5) * 16 + (br & 15);
    const __hip_bfloat16* wsel = (g & 1) ? w3 : w1;
    bSrc[j] = wsel + ((size_t)e * F_DIM + f) * H_DIM + chunk;
  }

  floatx4 acc[4][4];
#pragma unroll
  for (int i = 0; i < 4; ++i)
#pragma unroll
    for (int j = 0; j < 4; ++j) acc[i][j] = (floatx4)0.f;

#define STAGE1(OFF, K0)                                                     \
  {                                                                         \
    char* sb_ = smem + (OFF);                                               \
    _Pragma("unroll") for (int j = 0; j < 4; ++j)                           \
        gload_lds16(aSrc[j] + (K0), sb_ + j * 8192 + tid * 16);             \
    _Pragma("unroll") for (int j = 0; j < 2; ++j)                           \
        gload_lds16(bSrc[j] + (K0), sb_ + 32768 + j * 8192 + tid * 16);     \
  }

  const int NT = H_DIM / 64;  // 16
  STAGE1(0, 0);
  STAGE1(49152, 64);
  int curOff = 0, stgOff = 98304;
  for (int kt = 0; kt < NT; ++kt) {
    if (kt + 1 < NT)
      asm volatile("s_waitcnt vmcnt(6)" ::: "memory");  // tile kt landed, kt+1 (6) in flight
    else
      asm volatile("s_waitcnt vmcnt(0)" ::: "memory");
    __builtin_amdgcn_s_barrier();
    __builtin_amdgcn_sched_barrier(0);
    if (kt + 2 < NT) STAGE1(stgOff, (kt + 2) * 64);  // buf unused for 2 iterations: race-free
    const char* sb = smem + curOff;
    __builtin_amdgcn_s_setprio(1);
#pragma unroll
    for (int kk = 0; kk < 2; ++kk) {
      const int posx = ((kk * 4 + (lane >> 4)) ^ (lane & 7)) * 16;
      bf16x8 af[4], bf[4];
#pragma unroll
      for (int i = 0; i < 4; ++i)
        af[i] = *(const bf16x8*)(sb + (wm * 64 + i * 16 + (lane & 15)) * 128 + posx);
#pragma unroll
      for (int j = 0; j < 4; ++j)
        bf[j] = *(const bf16x8*)(sb + 32768 + (wn * 64 + j * 16 + (lane & 15)) * 128 + posx);
#pragma unroll
      for (int i = 0; i < 4; ++i)
#pragma unroll
        for (int j = 0; j < 4; ++j)
          acc[i][j] = __builtin_amdgcn_mfma_f32_16x16x32_bf16(af[i], bf[j], acc[i][j], 0, 0, 0);
    }
    __builtin_amdgcn_s_setprio(0);
    __builtin_amdgcn_sched_barrier(0);
    curOff += 49152;
    if (curOff == 147456) curOff = 0;
    stgOff += 49152;
    if (stgOff == 147456) stgOff = 0;
  }
#undef STAGE1

  // epilogue: j pairs (0,1)=(w1,w3)@F-block 2*wn, (2,3)@F-block 2*wn+1
#pragma unroll
  for (int i = 0; i < 4; ++i)
#pragma unroll
    for (int reg = 0; reg < 4; ++reg) {
      int rl = wm * 64 + i * 16 + (lane >> 4) * 4 + reg;
      int rg = mBase + rl;
      if (rg < Ne) {
        size_t slot = (size_t)offE + rg;
        int col = n0e + (2 * wn) * 16 + (lane & 15);
        float v1 = acc[i][0][reg], v3 = acc[i][1][reg];
        hbuf[slot * F_DIM + col] = __float2bfloat16(v1 / (1.f + __expf(-v1)) * v3);
        float u1 = acc[i][2][reg], u3 = acc[i][3][reg];
        hbuf[slot * F_DIM + col + 16] = __float2bfloat16(u1 / (1.f + __expf(-u1)) * u3);
      }
    }
}

// ---------------- K5: grouped GEMM2: 256 slots x 128 H-cols, K=3584, same skeleton ----------------
__global__ __launch_bounds__(512, 2) void k_gemm2(const __hip_bfloat16* __restrict__ hbuf,
                                                  const __hip_bfloat16* __restrict__ w2,
                                                  const int* __restrict__ count,
                                                  const int* __restrict__ offs,
                                                  const float* __restrict__ w_of_slot,
                                                  float* __restrict__ h2) {
  // launched grid (8, 16, 8) -> remap: wg = (lin%8)*128 + lin/8; y fastest, then x, then z
  const int lin = blockIdx.x + 8 * blockIdx.y + 128 * blockIdx.z;
  const int wg = (lin & 7) * 128 + (lin >> 3);
  const int yb = wg & 15;
  const int tq = wg >> 4;  // 0..63
  const int xb = tq & 7;
  const int e = tq >> 3;
  const int Ne = count[e];
  const int mBase = yb * 256;
  if (mBase >= Ne) return;
  const int offE = offs[e];
  const int n0 = xb * 128;       // H-col base
  __shared__ char smem[147456];  // 3 x (A 32K | B 16K)
  const int tid = threadIdx.x, lane = tid & 63, wv = tid >> 6;
  const int wm = wv >> 1, wn = wv & 1;
  const int chunk = (((tid & 7) ^ ((tid >> 3) & 7)) * 8);

  const __hip_bfloat16* aSrc[4];
#pragma unroll
  for (int j = 0; j < 4; ++j) {
    int rl = j * 64 + (tid >> 3);
    int slot = offE + mBase + rl;
    if (slot > NSLOT - 1) slot = NSLOT - 1;
    aSrc[j] = hbuf + (size_t)slot * F_DIM + chunk;
  }
  const __hip_bfloat16* bSrc[2];
#pragma unroll
  for (int j = 0; j < 2; ++j) {
    int br = j * 64 + (tid >> 3);
    bSrc[j] = w2 + ((size_t)e * H_DIM + n0 + br) * F_DIM + chunk;
  }

  floatx4 acc[4][4];
#pragma unroll
  for (int i = 0; i < 4; ++i)
#pragma unroll
    for (int j = 0; j < 4; ++j) acc[i][j] = (floatx4)0.f;

#define STAGE2(OFF, K0)                                                     \
  {                                                                         \
    char* sb_ = smem + (OFF);                                               \
    _Pragma("unroll") for (int j = 0; j < 4; ++j)                           \
        gload_lds16(aSrc[j] + (K0), sb_ + j * 8192 + tid * 16);             \
    _Pragma("unroll") for (int j = 0; j < 2; ++j)                           \
        gload_lds16(bSrc[j] + (K0), sb_ + 32768 + j * 8192 + tid * 16);     \
  }

  const int NT = F_DIM / 64;  // 56
  STAGE2(0, 0);
  STAGE2(49152, 64);
  int curOff = 0, stgOff = 98304;
  for (int kt = 0; kt < NT; ++kt) {
    if (kt + 1 < NT)
      asm volatile("s_waitcnt vmcnt(6)" ::: "memory");
    else
      asm volatile("s_waitcnt vmcnt(0)" ::: "memory");
    __builtin_amdgcn_s_barrier();
    __builtin_amdgcn_sched_barrier(0);
    if (kt + 2 < NT) STAGE2(stgOff, (kt + 2) * 64);
    const char* sb = smem + curOff;
    __builtin_amdgcn_s_setprio(1);
#pragma unroll
    for (int kk = 0; kk < 2; ++kk) {
      const int posx = ((kk * 4 + (lane >> 4)) ^ (lane & 7)) * 16;
      bf16x8 af[4], bf[4];
#pragma unroll
      for (int i = 0; i < 4; ++i)
        af[i] = *(const bf16x8*)(sb + (wm * 64 + i * 16 + (lane & 15)) * 128 + posx);
#pragma unroll
      for (int j = 0; j < 4; ++j)
        bf[j] = *(const bf16x8*)(sb + 32768 + (wn * 64 + j * 16 + (lane & 15)) * 128 + posx);
#pragma unroll
      for (int i = 0; i < 4; ++i)
#pragma unroll
        for (int j = 0; j < 4; ++j)
          acc[i][j] = __builtin_amdgcn_mfma_f32_16x16x32_bf16(af[i], bf[j], acc[i][j], 0, 0, 0);
    }
    __builtin_amdgcn_s_setprio(0);
    __builtin_amdgcn_sched_barrier(0);
    curOff += 49152;
    if (curOff == 147456) curOff = 0;
    stgOff += 49152;
    if (stgOff == 147456) stgOff = 0;
  }
#undef STAGE2

#pragma unroll
  for (int i = 0; i < 4; ++i)
#pragma unroll
    for (int reg = 0; reg < 4; ++reg) {
      int rl = wm * 64 + i * 16 + (lane >> 4) * 4 + reg;
      int rg = mBase + rl;
      if (rg < Ne) {
        size_t slot = (size_t)offE + rg;
        float wt = w_of_slot[slot];
#pragma unroll
        for (int j = 0; j < 4; ++j)
          h2[slot * H_DIM + n0 + wn * 64 + j * 16 + (lane & 15)] = acc[i][j][reg] * wt;
      }
    }
}

// ---------------- K6: combine per-token pair of slots -> fp32 out ----------------
__global__ __launch_bounds__(256) void k_combine(const float* __restrict__ h2,
                                                 const int* __restrict__ slot_of_tok,
                                                 float* __restrict__ out) {
  const int t = blockIdx.x;
  const int s0 = slot_of_tok[2 * t];
  const int s1 = slot_of_tok[2 * t + 1];
  const int n = threadIdx.x * 4;
  float4 a = *(const float4*)(h2 + (size_t)s0 * H_DIM + n);
  float4 b = *(const float4*)(h2 + (size_t)s1 * H_DIM + n);
  float4 v;
  v.x = a.x + b.x;
  v.y = a.y + b.y;
  v.z = a.z + b.z;
  v.w = a.w + b.w;
  *(float4*)(out + (size_t)t * H_DIM + n) = v;
}

extern "C" void kernel_launch(void* const* d_in, const int* in_sizes, int n_in,
                              void* d_out, int out_size, void* d_ws, size_t ws_size,
                              hipStream_t stream) {
  const float* x = (const float*)d_in[0];
  const float* gw = (const float*)d_in[1];
  const float* w1 = (const float*)d_in[2];
  const float* w2 = (const float*)d_in[3];
  const float* w3 = (const float*)d_in[4];
  float* out = (float*)d_out;

  char* ws = (char*)d_ws;
  int* count = (int*)(ws + 0);     // 8 ints
  int* cursor = (int*)(ws + 256);  // 8 ints
  int* offs = (int*)(ws + 512);    // 8 ints
  int* top2e = (int*)(ws + 4096);
  float* top2w = (float*)(ws + 4096 + 32768);
  int* tok_of_slot = (int*)(ws + 4096 + 65536);
  float* w_of_slot = (float*)(ws + 4096 + 98304);
  int* slot_of_tok = (int*)(ws + 4096 + 131072);
  char* big = ws + 167936;
  __hip_bfloat16* xb = (__hip_bfloat16*)(big);                   // 8 MB
  __hip_bfloat16* w1b = (__hip_bfloat16*)(big + 8388608);        // 58.7 MB
  __hip_bfloat16* w3b = (__hip_bfloat16*)(big + 67108864ULL);    // 58.7 MB
  __hip_bfloat16* w2b = (__hip_bfloat16*)(big + 125829120ULL);   // 58.7 MB
  __hip_bfloat16* hbuf = (__hip_bfloat16*)(big + 184549376ULL);  // 58.7 MB
  float* h2 = (float*)(big + 243269632ULL);                      // 33.5 MB

  const int n4_w = (E_NUM * F_DIM * H_DIM) / 4;  // 7340032

  hipMemsetAsync(ws, 0, 512, stream);  // zero count + cursor
  k_cast3<<<3 * n4_w / 256, 256, 0, stream>>>(w1, w2, w3, w1b, w2b, w3b, n4_w);
  k_router<<<T_TOK / 4, 256, 0, stream>>>(x, gw, xb, count, top2e, top2w);
  k_scan<<<1, 64, 0, stream>>>(count, offs);
  k_assign<<<T_TOK / 256, 256, 0, stream>>>(top2e, top2w, offs, cursor, tok_of_slot,
                                            w_of_slot, slot_of_tok);
  dim3 g1(F_DIM / 64, T_TOK / 256, E_NUM);
  k_gemm1<<<g1, 512, 0, stream>>>(xb, w1b, w3b, count, offs, tok_of_slot, hbuf);
  dim3 g2(H_DIM / 128, T_TOK / 256, E_NUM);
  k_gemm2<<<g2, 512, 0, stream>>>(hbuf, w2b, count, offs, w_of_slot, h2);
  k_combine<<<T_TOK, 256, 0, stream>>>(h2, slot_of_tok, out);
}

// Round 4
// 727.324 us; speedup vs baseline: 1.1269x; 1.1269x over previous
//
#include <hip/hip_runtime.h>
#include <hip/hip_bf16.h>
#include <math.h>

typedef __bf16 bf16x8 __attribute__((ext_vector_type(8)));
typedef float floatx4 __attribute__((ext_vector_type(4)));

#define T_TOK 4096
#define H_DIM 1024
#define F_DIM 3584
#define E_NUM 8
#define NSLOT 8192  // T_TOK * 2

__device__ __forceinline__ void gload_lds16(const void* g, void* l) {
  __builtin_amdgcn_global_load_lds((const __attribute__((address_space(1))) void*)g,
                                   (__attribute__((address_space(3))) void*)l, 16, 0, 0);
}

__device__ __forceinline__ uint2 pack_bf16x4(float4 v) {
  union {
    unsigned short us[4];
    uint2 u;
  } pk;
  __hip_bfloat16 h0 = __float2bfloat16(v.x);
  __hip_bfloat16 h1 = __float2bfloat16(v.y);
  __hip_bfloat16 h2 = __float2bfloat16(v.z);
  __hip_bfloat16 h3 = __float2bfloat16(v.w);
  pk.us[0] = *(const unsigned short*)&h0;
  pk.us[1] = *(const unsigned short*)&h1;
  pk.us[2] = *(const unsigned short*)&h2;
  pk.us[3] = *(const unsigned short*)&h3;
  return pk.u;
}

// ---------------- K0: cast the three weight tensors fp32 -> bf16, one launch ----------------
__global__ __launch_bounds__(256) void k_cast3(const float* __restrict__ a,
                                               const float* __restrict__ b,
                                               const float* __restrict__ c,
                                               __hip_bfloat16* __restrict__ oa,
                                               __hip_bfloat16* __restrict__ ob,
                                               __hip_bfloat16* __restrict__ oc, int n4) {
  int i = blockIdx.x * 256 + threadIdx.x;
  const float* src;
  __hip_bfloat16* dst;
  if (i < n4) {
    src = a;
    dst = oa;
  } else if (i < 2 * n4) {
    src = b;
    dst = ob;
    i -= n4;
  } else {
    src = c;
    dst = oc;
    i -= 2 * n4;
  }
  float4 v = ((const float4*)src)[i];
  ((uint2*)dst)[i] = pack_bf16x4(v);
}

// ---------------- K1: router (logits, softmax top-2, counts) + fused x cast ----------------
__global__ __launch_bounds__(256) void k_router(const float* __restrict__ x,
                                                const float* __restrict__ gw,
                                                __hip_bfloat16* __restrict__ xb,
                                                int* __restrict__ count,
                                                int* __restrict__ top2e,
                                                float* __restrict__ top2w) {
  const int lane = threadIdx.x & 63;
  const int wv = threadIdx.x >> 6;
  const int t = blockIdx.x * 4 + wv;
  const float4* xv = (const float4*)(x + (size_t)t * H_DIM);
  float4 xa[4];
#pragma unroll
  for (int p = 0; p < 4; ++p) xa[p] = xv[lane + p * 64];
  uint2* xo = (uint2*)(xb + (size_t)t * H_DIM);
#pragma unroll
  for (int p = 0; p < 4; ++p) xo[lane + p * 64] = pack_bf16x4(xa[p]);
  float s[E_NUM];
#pragma unroll
  for (int e = 0; e < E_NUM; ++e) {
    const float4* gv = (const float4*)(gw + e * H_DIM);
    float acc = 0.f;
#pragma unroll
    for (int p = 0; p < 4; ++p) {
      float4 g = gv[lane + p * 64];
      acc += xa[p].x * g.x + xa[p].y * g.y + xa[p].z * g.z + xa[p].w * g.w;
    }
    s[e] = acc;
  }
#pragma unroll
  for (int e = 0; e < E_NUM; ++e) {
#pragma unroll
    for (int m = 32; m; m >>= 1) s[e] += __shfl_xor(s[e], m);
  }
  if (lane == 0) {
    int e0 = 0;
    float l0 = s[0];
    for (int e = 1; e < E_NUM; ++e)
      if (s[e] > l0) { l0 = s[e]; e0 = e; }
    int e1 = (e0 == 0) ? 1 : 0;
    float l1 = s[e1];
    for (int e = 0; e < E_NUM; ++e)
      if (e != e0 && s[e] > l1) { l1 = s[e]; e1 = e; }
    float w0 = 1.f / (1.f + __expf(l1 - l0));
    float w1 = 1.f - w0;
    atomicAdd(&count[e0], 1);
    atomicAdd(&count[e1], 1);
    top2e[2 * t] = e0;
    top2e[2 * t + 1] = e1;
    top2w[2 * t] = w0;
    top2w[2 * t + 1] = w1;
  }
}

// ---------------- K2: exclusive scan of 8 counts ----------------
__global__ void k_scan(const int* __restrict__ count, int* __restrict__ offs) {
  if (threadIdx.x == 0) {
    int a = 0;
    for (int e = 0; e < E_NUM; ++e) { offs[e] = a; a += count[e]; }
  }
}

// ---------------- K3: slot assignment ----------------
__global__ __launch_bounds__(256) void k_assign(const int* __restrict__ top2e,
                                                const float* __restrict__ top2w,
                                                const int* __restrict__ offs,
                                                int* __restrict__ cursor,
                                                int* __restrict__ tok_of_slot,
                                                float* __restrict__ w_of_slot,
                                                int* __restrict__ slot_of_tok) {
  const int t = blockIdx.x * 256 + threadIdx.x;
#pragma unroll
  for (int k = 0; k < 2; ++k) {
    int e = top2e[2 * t + k];
    int pos = atomicAdd(&cursor[e], 1);
    int slot = offs[e] + pos;
    tok_of_slot[slot] = t;
    w_of_slot[slot] = top2w[2 * t + k];
    slot_of_tok[2 * t + k] = slot;
  }
}

// ---------------- K4: grouped GEMM1 (X @ w1^T, X @ w3^T, silu*mul) ----------------
// R0-proven structure: tile 128 slots x 64 F-cols, K-step 64, 4 waves 2x2, 32KB LDS,
// ~2.5 blocks/CU -> inter-wave overlap does the latency hiding. 160us / 35% MfmaUtil.
__global__ __launch_bounds__(256) void k_gemm1(const __hip_bfloat16* __restrict__ x,
                                               const __hip_bfloat16* __restrict__ w1,
                                               const __hip_bfloat16* __restrict__ w3,
                                               const int* __restrict__ count,
                                               const int* __restrict__ offs,
                                               const int* __restrict__ tok_of_slot,
                                               __hip_bfloat16* __restrict__ hbuf) {
  const int e = blockIdx.z;
  const int Ne = count[e];
  const int mBase = blockIdx.y * 128;
  if (mBase >= Ne) return;
  const int offE = offs[e];
  const int n0 = blockIdx.x * 64;
  __shared__ char smem[32768];  // A 16K | B1 8K | B3 8K
  const int tid = threadIdx.x, lane = tid & 63, wv = tid >> 6;
  const int wm = wv >> 1, wn = wv & 1;
  const int srcOff = ((lane & 7) ^ (lane >> 3)) * 8;  // XOR-swizzled source chunk (elements)

  const __hip_bfloat16* aSrc[4];
#pragma unroll
  for (int j = 0; j < 4; ++j) {
    int rl = wv * 32 + j * 8 + (lane >> 3);
    int slot = offE + mBase + rl;
    if (slot > NSLOT - 1) slot = NSLOT - 1;
    int tok = tok_of_slot[slot];
    aSrc[j] = x + (size_t)tok * H_DIM + srcOff;
  }
  const __hip_bfloat16 *b1Src[2], *b3Src[2];
#pragma unroll
  for (int j = 0; j < 2; ++j) {
    int rl = wv * 16 + j * 8 + (lane >> 3);
    size_t row = (size_t)e * F_DIM + n0 + rl;
    b1Src[j] = w1 + row * H_DIM + srcOff;
    b3Src[j] = w3 + row * H_DIM + srcOff;
  }

  floatx4 acc1[4][2], acc3[4][2];
#pragma unroll
  for (int i = 0; i < 4; ++i)
#pragma unroll
    for (int j = 0; j < 2; ++j) {
      acc1[i][j] = (floatx4)0.f;
      acc3[i][j] = (floatx4)0.f;
    }

  for (int kt = 0; kt < H_DIM / 64; ++kt) {
    const int k0 = kt * 64;
#pragma unroll
    for (int j = 0; j < 4; ++j)
      gload_lds16(aSrc[j] + k0, smem + wv * 4096 + j * 1024 + lane * 16);
#pragma unroll
    for (int j = 0; j < 2; ++j) {
      gload_lds16(b1Src[j] + k0, smem + 16384 + wv * 2048 + j * 1024 + lane * 16);
      gload_lds16(b3Src[j] + k0, smem + 24576 + wv * 2048 + j * 1024 + lane * 16);
    }
    __syncthreads();
#pragma unroll
    for (int kk = 0; kk < 2; ++kk) {
      bf16x8 af[4], b1f[2], b3f[2];
      const int posx = ((kk * 4 + (lane >> 4)) ^ (lane & 7)) * 16;
#pragma unroll
      for (int i = 0; i < 4; ++i) {
        int r = wm * 64 + i * 16 + (lane & 15);
        af[i] = *(const bf16x8*)(smem + r * 128 + posx);
      }
#pragma unroll
      for (int j = 0; j < 2; ++j) {
        int r = wn * 32 + j * 16 + (lane & 15);
        b1f[j] = *(const bf16x8*)(smem + 16384 + r * 128 + posx);
        b3f[j] = *(const bf16x8*)(smem + 24576 + r * 128 + posx);
      }
#pragma unroll
      for (int i = 0; i < 4; ++i)
#pragma unroll
        for (int j = 0; j < 2; ++j) {
          acc1[i][j] = __builtin_amdgcn_mfma_f32_16x16x32_bf16(af[i], b1f[j], acc1[i][j], 0, 0, 0);
          acc3[i][j] = __builtin_amdgcn_mfma_f32_16x16x32_bf16(af[i], b3f[j], acc3[i][j], 0, 0, 0);
        }
    }
    __syncthreads();
  }
  // epilogue: h = silu(h1) * h3 -> bf16
#pragma unroll
  for (int i = 0; i < 4; ++i)
#pragma unroll
    for (int reg = 0; reg < 4; ++reg) {
      int rl = wm * 64 + i * 16 + (lane >> 4) * 4 + reg;
      int rg = mBase + rl;
      if (rg < Ne) {
        size_t slot = (size_t)offE + rg;
#pragma unroll
        for (int j = 0; j < 2; ++j) {
          float v1 = acc1[i][j][reg], v3 = acc3[i][j][reg];
          float hv = v1 / (1.f + __expf(-v1)) * v3;
          hbuf[slot * F_DIM + n0 + wn * 32 + j * 16 + (lane & 15)] = __float2bfloat16(hv);
        }
      }
    }
}

// ---------------- K5: grouped GEMM2 (h @ w2^T, scaled, fused combine via atomicAdd) ----------------
// R0 loop structure. XCD-chunked bijective swizzle (nwg=4096, 512/XCD = one expert/XCD;
// x fastest within chunk -> A-panel (hbuf) L2 reuse across the 16 x-blocks).
// Epilogue: out[tok] += acc*wt (each element gets exactly 2 contributions; 2-term fp32 add
// is order-independent -> bit-identical to the separate combine kernel).
__global__ __launch_bounds__(256) void k_gemm2(const __hip_bfloat16* __restrict__ hbuf,
                                               const __hip_bfloat16* __restrict__ w2,
                                               const int* __restrict__ count,
                                               const int* __restrict__ offs,
                                               const float* __restrict__ w_of_slot,
                                               const int* __restrict__ tok_of_slot,
                                               float* __restrict__ out) {
  // launched grid (16, 32, 8); remap lin -> wg so each XCD owns one expert, x fastest
  const int lin = blockIdx.x + 16 * blockIdx.y + 512 * blockIdx.z;
  const int wg = (lin & 7) * 512 + (lin >> 3);
  const int xb = wg & 15;
  const int yb = (wg >> 4) & 31;
  const int e = wg >> 9;
  const int Ne = count[e];
  const int mBase = yb * 128;
  if (mBase >= Ne) return;
  const int offE = offs[e];
  const int n0 = xb * 64;
  __shared__ char smem[24576];  // A 16K | B 8K
  const int tid = threadIdx.x, lane = tid & 63, wv = tid >> 6;
  const int wm = wv >> 1, wn = wv & 1;
  const int srcOff = ((lane & 7) ^ (lane >> 3)) * 8;

  const __hip_bfloat16* aSrc[4];
#pragma unroll
  for (int j = 0; j < 4; ++j) {
    int rl = wv * 32 + j * 8 + (lane >> 3);
    int slot = offE + mBase + rl;
    if (slot > NSLOT - 1) slot = NSLOT - 1;
    aSrc[j] = hbuf + (size_t)slot * F_DIM + srcOff;
  }
  const __hip_bfloat16* bSrc[2];
#pragma unroll
  for (int j = 0; j < 2; ++j) {
    int rl = wv * 16 + j * 8 + (lane >> 3);
    bSrc[j] = w2 + ((size_t)e * H_DIM + n0 + rl) * F_DIM + srcOff;
  }

  floatx4 acc[4][2];
#pragma unroll
  for (int i = 0; i < 4; ++i)
#pragma unroll
    for (int j = 0; j < 2; ++j) acc[i][j] = (floatx4)0.f;

  for (int kt = 0; kt < F_DIM / 64; ++kt) {
    const int k0 = kt * 64;
#pragma unroll
    for (int j = 0; j < 4; ++j)
      gload_lds16(aSrc[j] + k0, smem + wv * 4096 + j * 1024 + lane * 16);
#pragma unroll
    for (int j = 0; j < 2; ++j)
      gload_lds16(bSrc[j] + k0, smem + 16384 + wv * 2048 + j * 1024 + lane * 16);
    __syncthreads();
#pragma unroll
    for (int kk = 0; kk < 2; ++kk) {
      bf16x8 af[4], bf[2];
      const int posx = ((kk * 4 + (lane >> 4)) ^ (lane & 7)) * 16;
#pragma unroll
      for (int i = 0; i < 4; ++i) {
        int r = wm * 64 + i * 16 + (lane & 15);
        af[i] = *(const bf16x8*)(smem + r * 128 + posx);
      }
#pragma unroll
      for (int j = 0; j < 2; ++j) {
        int r = wn * 32 + j * 16 + (lane & 15);
        bf[j] = *(const bf16x8*)(smem + 16384 + r * 128 + posx);
      }
#pragma unroll
      for (int i = 0; i < 4; ++i)
#pragma unroll
        for (int j = 0; j < 2; ++j)
          acc[i][j] = __builtin_amdgcn_mfma_f32_16x16x32_bf16(af[i], bf[j], acc[i][j], 0, 0, 0);
    }
    __syncthreads();
  }
#pragma unroll
  for (int i = 0; i < 4; ++i)
#pragma unroll
    for (int reg = 0; reg < 4; ++reg) {
      int rl = wm * 64 + i * 16 + (lane >> 4) * 4 + reg;
      int rg = mBase + rl;
      if (rg < Ne) {
        size_t slot = (size_t)offE + rg;
        float wt = w_of_slot[slot];
        int tok = tok_of_slot[slot];
#pragma unroll
        for (int j = 0; j < 2; ++j) {
          int col = n0 + wn * 32 + j * 16 + (lane & 15);
          atomicAdd(out + (size_t)tok * H_DIM + col, acc[i][j][reg] * wt);
        }
      }
    }
}

extern "C" void kernel_launch(void* const* d_in, const int* in_sizes, int n_in,
                              void* d_out, int out_size, void* d_ws, size_t ws_size,
                              hipStream_t stream) {
  const float* x = (const float*)d_in[0];
  const float* gw = (const float*)d_in[1];
  const float* w1 = (const float*)d_in[2];
  const float* w2 = (const float*)d_in[3];
  const float* w3 = (const float*)d_in[4];
  float* out = (float*)d_out;

  char* ws = (char*)d_ws;
  int* count = (int*)(ws + 0);     // 8 ints
  int* cursor = (int*)(ws + 256);  // 8 ints
  int* offs = (int*)(ws + 512);    // 8 ints
  int* top2e = (int*)(ws + 4096);
  float* top2w = (float*)(ws + 4096 + 32768);
  int* tok_of_slot = (int*)(ws + 4096 + 65536);
  float* w_of_slot = (float*)(ws + 4096 + 98304);
  int* slot_of_tok = (int*)(ws + 4096 + 131072);
  char* big = ws + 167936;
  __hip_bfloat16* xb = (__hip_bfloat16*)(big);                   // 8 MB
  __hip_bfloat16* w1b = (__hip_bfloat16*)(big + 8388608);        // 58.7 MB
  __hip_bfloat16* w3b = (__hip_bfloat16*)(big + 67108864ULL);    // 58.7 MB
  __hip_bfloat16* w2b = (__hip_bfloat16*)(big + 125829120ULL);   // 58.7 MB
  __hip_bfloat16* hbuf = (__hip_bfloat16*)(big + 184549376ULL);  // 58.7 MB

  const int n4_w = (E_NUM * F_DIM * H_DIM) / 4;  // 7340032

  hipMemsetAsync(ws, 0, 512, stream);  // zero count + cursor
  hipMemsetAsync(out, 0, (size_t)T_TOK * H_DIM * 4, stream);  // accumulate target
  k_cast3<<<3 * n4_w / 256, 256, 0, stream>>>(w1, w2, w3, w1b, w2b, w3b, n4_w);
  k_router<<<T_TOK / 4, 256, 0, stream>>>(x, gw, xb, count, top2e, top2w);
  k_scan<<<1, 64, 0, stream>>>(count, offs);
  k_assign<<<T_TOK / 256, 256, 0, stream>>>(top2e, top2w, offs, cursor, tok_of_slot,
                                            w_of_slot, slot_of_tok);
  dim3 g1(F_DIM / 64, T_TOK / 128, E_NUM);
  k_gemm1<<<g1, 256, 0, stream>>>(xb, w1b, w3b, count, offs, tok_of_slot, hbuf);
  dim3 g2(H_DIM / 64, T_TOK / 128, E_NUM);
  k_gemm2<<<g2, 256, 0, stream>>>(hbuf, w2b, count, offs, w_of_slot, tok_of_slot, out);
}